// Round 2
// baseline (399.296 us; speedup 1.0000x reference)
//
#include <hip/hip_runtime.h>
#include <stdint.h>

// Problem constants
#define HH 32
#define WW 32
#define CC 512
#define CLS 1000
#define RR 64
#define BB 128
#define KK 1024            // W*H
#define MM (BB*CC)         // 65536 rows of x_flat

#define KSPLIT 4
#define KS (KK/KSPLIT)     // 256 k per block
#define QS (KS/32)         // 8 mfma k-chunks per block
#define NPART 32           // partials per b: 8 x-groups * 4 k-slices

typedef __bf16  bf16x8 __attribute__((ext_vector_type(8)));
typedef float   f32x4  __attribute__((ext_vector_type(4)));
typedef uint32_t u32x4 __attribute__((ext_vector_type(4)));

// ---------------------------------------------------------------------------
// Prep: V[k, r] = U2[w,r]*U1[h,r]  (k = w*32 + h), stored pre-permuted into
// MFMA B-fragment order: Vf[((q*4 + f)*64 + lane)*8 + j] holds
// V[k = 32q + (lane>>4)*8 + j][n = 16f + (lane&15)]  as bf16.
// ---------------------------------------------------------------------------
__global__ void prep_v(const float* __restrict__ U1, const float* __restrict__ U2,
                       __bf16* __restrict__ Vf) {
    int idx = blockIdx.x * 256 + threadIdx.x;   // 0..8191  == (q*4+f)*64 + lane
    int l  = idx & 63;
    int qf = idx >> 6;
    int f  = qf & 3;
    int q  = qf >> 2;
    int n  = f * 16 + (l & 15);
    int kb = q * 32 + (l >> 4) * 8;
#pragma unroll
    for (int j = 0; j < 8; ++j) {
        int k = kb + j;
        int w = k >> 5, h = k & 31;
        float v = U2[w * RR + n] * U1[h * RR + n];
        Vf[(size_t)idx * 8 + j] = (__bf16)v;
    }
}

// ---------------------------------------------------------------------------
// Main: t3p[p,b,r] = sum_{c in block} U3[c,r] * sum_{k in slice} x[m,k]*V[k,r]
// grid (MM/64, KSPLIT), block 256 (4 waves). Wave w handles rows 16w..16w+15.
// A loaded straight from global in fragment layout (no LDS, no K-loop barrier),
// B fragments ds_read from LDS (staged once per block). U3 hoisted to regs
// before the K-loop. Plain partial stores, no atomics, no memset needed.
// ---------------------------------------------------------------------------
__global__ void __launch_bounds__(256)
main_k(const float* __restrict__ x, const __bf16* __restrict__ Vf,
       const float* __restrict__ U3, float* __restrict__ t3p) {
    __shared__ alignas(16) __bf16 vs[QS * 4 * 64 * 8];   // 32 KB
    __shared__ float red[4][64];

    // Stage this block's K-slice of Vf (contiguous 32 KB) into LDS.
    {
        const u32x4* src = (const u32x4*)(Vf + (size_t)blockIdx.y * QS * 4 * 64 * 8);
        u32x4* dst = (u32x4*)vs;
#pragma unroll
        for (int i = 0; i < 8; ++i)
            dst[threadIdx.x + i * 256] = src[threadIdx.x + i * 256];
    }

    const int tid = threadIdx.x;
    const int wv  = tid >> 6;
    const int l   = tid & 63;
    const int m   = blockIdx.x * 64 + wv * 16 + (l & 15);   // global row (b*512+c)
    const int k0  = blockIdx.y * KS;

    const float* xp = x + (size_t)m * KK + k0 + ((l >> 4) * 8);

    // Hoist U3 weights into registers (consumed in the epilogue; latency
    // hides under the K-loop's load/MFMA stream).
    const int c_l = ((blockIdx.x * 64) & (CC - 1)) + wv * 16 + (l >> 4) * 4;
    float u3r[4][4];
#pragma unroll
    for (int f = 0; f < 4; ++f) {
        int r = f * 16 + (l & 15);
#pragma unroll
        for (int i = 0; i < 4; ++i)
            u3r[f][i] = U3[(c_l + i) * RR + r];
    }

    __syncthreads();

    f32x4 acc[4] = {};
#pragma unroll
    for (int q = 0; q < QS; ++q) {
        f32x4 a0 = *(const f32x4*)(xp + q * 32);
        f32x4 a1 = *(const f32x4*)(xp + q * 32 + 4);
        bf16x8 af;
        af[0] = (__bf16)a0.x; af[1] = (__bf16)a0.y;
        af[2] = (__bf16)a0.z; af[3] = (__bf16)a0.w;
        af[4] = (__bf16)a1.x; af[5] = (__bf16)a1.y;
        af[6] = (__bf16)a1.z; af[7] = (__bf16)a1.w;
#pragma unroll
        for (int f = 0; f < 4; ++f) {
            bf16x8 bf = ((const bf16x8*)vs)[(q * 4 + f) * 64 + l];
            acc[f] = __builtin_amdgcn_mfma_f32_16x16x32_bf16(af, bf, acc[f], 0, 0, 0);
        }
    }

    // Epilogue: weight by U3[c,r], reduce 16 rows (in-lane) + 4 row-quads
    // (shfl) + 4 waves (LDS), one plain store per (p,b,r).
    float p[4];
#pragma unroll
    for (int f = 0; f < 4; ++f) {
        float s = 0.f;
#pragma unroll
        for (int i = 0; i < 4; ++i)
            s += acc[f][i] * u3r[f][i];
        p[f] = s;
    }
#pragma unroll
    for (int f = 0; f < 4; ++f) {
        p[f] += __shfl_xor(p[f], 16, 64);
        p[f] += __shfl_xor(p[f], 32, 64);
    }
    if (l < 16) {
#pragma unroll
        for (int f = 0; f < 4; ++f) red[wv][f * 16 + l] = p[f];
    }
    __syncthreads();
    if (tid < 64) {
        const int b    = blockIdx.x >> 3;
        const int part = blockIdx.y * 8 + (blockIdx.x & 7);
        float s = red[0][tid] + red[1][tid] + red[2][tid] + red[3][tid];
        t3p[((size_t)part * BB + b) * RR + tid] = s;
    }
}

// ---------------------------------------------------------------------------
// Final: out[b,cls] = sum_r (sum_p t3p[p,b,r]) * lam[r] * U4[cls,r]
// grid (4, 8): bx tiles cls by 256, by tiles b by 16. U4 row held in regs.
// ---------------------------------------------------------------------------
__global__ void out_k(const float* __restrict__ t3p, const float* __restrict__ lam,
                      const float* __restrict__ U4, float* __restrict__ out) {
    __shared__ float sl[16 * RR];   // 4 KB: (b_local, r), lam pre-applied
    const int tid = threadIdx.x;
    const int by  = blockIdx.y;

    // Sum 32 partials, apply lam. 256 threads cover 16*16 float4 groups.
    {
        const int bl = tid >> 4;          // 0..15 b_local
        const int rg = tid & 15;          // 0..15 float4 group
        const int b  = by * 16 + bl;
        f32x4 s = {};
#pragma unroll
        for (int p = 0; p < NPART; ++p)
            s += *(const f32x4*)(t3p + ((size_t)p * BB + b) * RR + rg * 4);
        const f32x4 lm = *(const f32x4*)(lam + rg * 4);
        s *= lm;
        *(f32x4*)(sl + bl * RR + rg * 4) = s;
    }
    __syncthreads();

    const int cls = blockIdx.x * 256 + tid;
    if (cls >= CLS) return;
    f32x4 u[16];
    const f32x4* u4 = (const f32x4*)(U4 + (size_t)cls * RR);
#pragma unroll
    for (int i = 0; i < 16; ++i) u[i] = u4[i];
#pragma unroll
    for (int bl = 0; bl < 16; ++bl) {
        const float* s0 = sl + bl * RR;
        float s = 0.f;
#pragma unroll
        for (int i = 0; i < 16; ++i) {
            f32x4 v = u[i];
            s += v.x * s0[i*4+0] + v.y * s0[i*4+1] + v.z * s0[i*4+2] + v.w * s0[i*4+3];
        }
        out[(size_t)(by * 16 + bl) * CLS + cls] = s;
    }
}

// ---------------------------------------------------------------------------
extern "C" void kernel_launch(void* const* d_in, const int* in_sizes, int n_in,
                              void* d_out, int out_size, void* d_ws, size_t ws_size,
                              hipStream_t stream) {
    const float* x   = (const float*)d_in[0];
    const float* U1  = (const float*)d_in[1];
    const float* U2  = (const float*)d_in[2];
    const float* U3  = (const float*)d_in[3];
    const float* U4  = (const float*)d_in[4];
    const float* lam = (const float*)d_in[5];

    __bf16* Vf  = (__bf16*)d_ws;                          // 128 KB
    float*  t3p = (float*)((char*)d_ws + 128 * 1024);     // 1 MB (32*128*64 f32)
    float*  out = (float*)d_out;

    prep_v<<<32, 256, 0, stream>>>(U1, U2, Vf);
    main_k<<<dim3(MM / 64, KSPLIT), 256, 0, stream>>>(x, Vf, U3, t3p);
    out_k<<<dim3(4, 8), 256, 0, stream>>>(t3p, lam, U4, out);
}

// Round 3
// 392.744 us; speedup vs baseline: 1.0167x; 1.0167x over previous
//
#include <hip/hip_runtime.h>
#include <stdint.h>

// Problem constants
#define HH 32
#define WW 32
#define CC 512
#define CLS 1000
#define RR 64
#define BB 128
#define KK 1024            // W*H
#define MM (BB*CC)         // 65536 rows of x_flat

#define KSPLIT 4
#define KS (KK/KSPLIT)     // 256 k per block
#define QS (KS/32)         // 8 mfma k-chunks per block
#define NPART 32           // partials per b: 8 x-groups * 4 k-slices

typedef __bf16  bf16x8 __attribute__((ext_vector_type(8)));
typedef float   f32x4  __attribute__((ext_vector_type(4)));

// ---------------------------------------------------------------------------
// Prep: V[k, r] = U2[w,r]*U1[h,r]  (k = w*32 + h), stored pre-permuted into
// MFMA B-fragment order: Vf[((q*4 + f)*64 + lane)*8 + j] holds
// V[k = 32q + (lane>>4)*8 + j][n = 16f + (lane&15)]  as bf16,
// where q here indexes the FULL K range (0..31).
// ---------------------------------------------------------------------------
__global__ void prep_v(const float* __restrict__ U1, const float* __restrict__ U2,
                       __bf16* __restrict__ Vf) {
    int idx = blockIdx.x * 256 + threadIdx.x;   // 0..8191  == (q*4+f)*64 + lane
    int l  = idx & 63;
    int qf = idx >> 6;
    int f  = qf & 3;
    int q  = qf >> 2;
    int n  = f * 16 + (l & 15);
    int kb = q * 32 + (l >> 4) * 8;
#pragma unroll
    for (int j = 0; j < 8; ++j) {
        int k = kb + j;
        int w = k >> 5, h = k & 31;
        float v = U2[w * RR + n] * U1[h * RR + n];
        Vf[(size_t)idx * 8 + j] = (__bf16)v;
    }
}

// ---------------------------------------------------------------------------
// Main: t3p[p,b,r] = sum_{c in block} U3[c,r] * sum_{k in slice} x[m,k]*V[k,r]
// grid (MM/64, KSPLIT), block 256 (4 waves). Wave w handles rows 16w..16w+15.
// A loaded straight from global in fragment layout; B fragments loaded
// straight from global too (Vf is 128 KB -> L2-resident; lane-contiguous
// dwordx4). NO LDS staging, NO K-loop barriers -> occupancy is VGPR-limited
// and every wave issues x-loads immediately.
// ---------------------------------------------------------------------------
__global__ void __launch_bounds__(256)
main_k(const float* __restrict__ x, const __bf16* __restrict__ Vf,
       const float* __restrict__ U3, float* __restrict__ t3p) {
    __shared__ float red[4][64];

    const int tid = threadIdx.x;
    const int wv  = tid >> 6;
    const int l   = tid & 63;
    const int m   = blockIdx.x * 64 + wv * 16 + (l & 15);   // global row (b*512+c)
    const int k0  = blockIdx.y * KS;

    const float* xp = x + (size_t)m * KK + k0 + ((l >> 4) * 8);
    // B fragments for this block's K-slice, this lane:
    const bf16x8* vp = (const bf16x8*)Vf + (size_t)(blockIdx.y * QS * 4) * 64 + l;

    // Hoist U3 weights into registers (consumed in the epilogue; latency
    // hides under the K-loop's load/MFMA stream).
    const int c_l = ((blockIdx.x * 64) & (CC - 1)) + wv * 16 + (l >> 4) * 4;
    float u3r[4][4];
#pragma unroll
    for (int f = 0; f < 4; ++f) {
        int r = f * 16 + (l & 15);
#pragma unroll
        for (int i = 0; i < 4; ++i)
            u3r[f][i] = U3[(c_l + i) * RR + r];
    }

    f32x4 acc[4] = {};
#pragma unroll
    for (int q = 0; q < QS; ++q) {
        f32x4 a0 = *(const f32x4*)(xp + q * 32);
        f32x4 a1 = *(const f32x4*)(xp + q * 32 + 4);
        bf16x8 af;
        af[0] = (__bf16)a0.x; af[1] = (__bf16)a0.y;
        af[2] = (__bf16)a0.z; af[3] = (__bf16)a0.w;
        af[4] = (__bf16)a1.x; af[5] = (__bf16)a1.y;
        af[6] = (__bf16)a1.z; af[7] = (__bf16)a1.w;
#pragma unroll
        for (int f = 0; f < 4; ++f) {
            bf16x8 bf = vp[(q * 4 + f) * 64];
            acc[f] = __builtin_amdgcn_mfma_f32_16x16x32_bf16(af, bf, acc[f], 0, 0, 0);
        }
    }

    // Epilogue: weight by U3[c,r], reduce 16 rows (in-lane) + 4 row-quads
    // (shfl) + 4 waves (LDS), one plain store per (p,b,r).
    float p[4];
#pragma unroll
    for (int f = 0; f < 4; ++f) {
        float s = 0.f;
#pragma unroll
        for (int i = 0; i < 4; ++i)
            s += acc[f][i] * u3r[f][i];
        p[f] = s;
    }
#pragma unroll
    for (int f = 0; f < 4; ++f) {
        p[f] += __shfl_xor(p[f], 16, 64);
        p[f] += __shfl_xor(p[f], 32, 64);
    }
    if (l < 16) {
#pragma unroll
        for (int f = 0; f < 4; ++f) red[wv][f * 16 + l] = p[f];
    }
    __syncthreads();
    if (tid < 64) {
        const int b    = blockIdx.x >> 3;
        const int part = blockIdx.y * 8 + (blockIdx.x & 7);
        float s = red[0][tid] + red[1][tid] + red[2][tid] + red[3][tid];
        t3p[((size_t)part * BB + b) * RR + tid] = s;
    }
}

// ---------------------------------------------------------------------------
// Final: out[b,cls] = sum_r (sum_p t3p[p,b,r]) * lam[r] * U4[cls,r]
// grid (4, 8): bx tiles cls by 256, by tiles b by 16. U4 row held in regs.
// ---------------------------------------------------------------------------
__global__ void out_k(const float* __restrict__ t3p, const float* __restrict__ lam,
                      const float* __restrict__ U4, float* __restrict__ out) {
    __shared__ float sl[16 * RR];   // 4 KB: (b_local, r), lam pre-applied
    const int tid = threadIdx.x;
    const int by  = blockIdx.y;

    // Sum 32 partials, apply lam. 256 threads cover 16*16 float4 groups.
    {
        const int bl = tid >> 4;          // 0..15 b_local
        const int rg = tid & 15;          // 0..15 float4 group
        const int b  = by * 16 + bl;
        f32x4 s = {};
#pragma unroll
        for (int p = 0; p < NPART; ++p)
            s += *(const f32x4*)(t3p + ((size_t)p * BB + b) * RR + rg * 4);
        const f32x4 lm = *(const f32x4*)(lam + rg * 4);
        s *= lm;
        *(f32x4*)(sl + bl * RR + rg * 4) = s;
    }
    __syncthreads();

    const int cls = blockIdx.x * 256 + tid;
    if (cls >= CLS) return;
    f32x4 u[16];
    const f32x4* u4 = (const f32x4*)(U4 + (size_t)cls * RR);
#pragma unroll
    for (int i = 0; i < 16; ++i) u[i] = u4[i];
#pragma unroll
    for (int bl = 0; bl < 16; ++bl) {
        const float* s0 = sl + bl * RR;
        float s = 0.f;
#pragma unroll
        for (int i = 0; i < 16; ++i) {
            f32x4 v = u[i];
            s += v.x * s0[i*4+0] + v.y * s0[i*4+1] + v.z * s0[i*4+2] + v.w * s0[i*4+3];
        }
        out[(size_t)(by * 16 + bl) * CLS + cls] = s;
    }
}

// ---------------------------------------------------------------------------
extern "C" void kernel_launch(void* const* d_in, const int* in_sizes, int n_in,
                              void* d_out, int out_size, void* d_ws, size_t ws_size,
                              hipStream_t stream) {
    const float* x   = (const float*)d_in[0];
    const float* U1  = (const float*)d_in[1];
    const float* U2  = (const float*)d_in[2];
    const float* U3  = (const float*)d_in[3];
    const float* U4  = (const float*)d_in[4];
    const float* lam = (const float*)d_in[5];

    __bf16* Vf  = (__bf16*)d_ws;                          // 128 KB
    float*  t3p = (float*)((char*)d_ws + 128 * 1024);     // 1 MB (32*128*64 f32)
    float*  out = (float*)d_out;

    prep_v<<<32, 256, 0, stream>>>(U1, U2, Vf);
    main_k<<<dim3(MM / 64, KSPLIT), 256, 0, stream>>>(x, Vf, U3, t3p);
    out_k<<<dim3(4, 8), 256, 0, stream>>>(t3p, lam, U4, out);
}